// Round 6
// baseline (1378.101 us; speedup 1.0000x reference)
//
#include <hip/hip_runtime.h>
#include <hip/hip_bf16.h>
#include <cstdint>

typedef __bf16 bf16x8 __attribute__((ext_vector_type(8)));
typedef float  f32x4  __attribute__((ext_vector_type(4)));

struct alignas(4) us2 { unsigned short x, y; };
struct alignas(8) us4 { unsigned short x, y, z, w; };

__device__ __forceinline__ unsigned short f2bf(float f) {
    union { float f; unsigned u; } a; a.f = f;
    unsigned r = a.u + 0x7fffu + ((a.u >> 16) & 1u);   // round-to-nearest-even
    return (unsigned short)(r >> 16);
}

__device__ __forceinline__ void gl_lds16(const void* g, void* s) {
    __builtin_amdgcn_global_load_lds(
        (const __attribute__((address_space(1))) void*)g,
        (__attribute__((address_space(3))) void*)s, 16, 0, 0);
}

#define SBAR()    do { __builtin_amdgcn_sched_barrier(0); __builtin_amdgcn_s_barrier(); __builtin_amdgcn_sched_barrier(0); } while (0)
#define WAITLG(N) do { asm volatile("s_waitcnt lgkmcnt(" #N ")" ::: "memory"); __builtin_amdgcn_sched_barrier(0); } while (0)
#define WAITVM(N) do { asm volatile("s_waitcnt vmcnt(" #N ")" ::: "memory"); __builtin_amdgcn_sched_barrier(0); } while (0)

// C = A(MxK) @ W(NxK)^T, bf16 in, fp32 acc. 256xBN tile, BK=32, 8 waves (2Mx4N).
// DOUBLE-buffered LDS (2 slots; 64KB at BN=256, 48KB at BN=128) -> 2 blocks/CU:
// cross-block TLP covers the tile-top drain (m114/m97 mechanism). Stage tile k+1
// during tile k; tile-top vmcnt(0) waits ~1-tile-old loads only.
// Intra-tile: ds_reads pipelined one MFMA-step ahead, counted lgkmcnt(2), setprio.
// LDS swizzle v2 (0 bank conflicts): chunk-col ^= (row>>1)&3.
// EPI 0: outb = bf16(gelu_exact(acc+bias)) ; EPI 1: outf = acc+bias ;
// EPI 2: fused coupling (W interleaved s/t): even col -> s, odd -> t.
template<int EPI, int K, int N, int BN>
__global__ __launch_bounds__(512, 4)
void gemm256(const unsigned short* __restrict__ A,
             const unsigned short* __restrict__ W,
             const float* __restrict__ bias,
             unsigned short* __restrict__ outb,
             float* __restrict__ outf,
             const float* __restrict__ zin,
             float* __restrict__ ldout)
{
    extern __shared__ char smem[];
    constexpr int NT = K / 32;
    constexpr int GX = N / BN;
    constexpr int NI = BN / 64;            // B frags per wave
    constexpr int BSLOT = BN * 64;         // bytes per B slot

    const int tid  = threadIdx.x;
    const int lane = tid & 63;
    const int wv   = tid >> 6;             // 0..7
    const int wr   = wv >> 2, wc = wv & 3;

    // T1: bijective XCD swizzle (nwg divisible by 8 for all our shapes)
    const int bid = blockIdx.y * GX + blockIdx.x;
    const int nwg = GX * (int)gridDim.y;
    const int swz = (bid & 7) * (nwg >> 3) + (bid >> 3);
    const size_t row0 = (size_t)(swz / GX) * 256;
    const size_t col0 = (size_t)(swz % GX) * BN;

    char* sA = smem;               // 2 slots x 16KB
    char* sB = smem + 32768;       // 2 slots x BSLOT

    // staging: thread tid stages LDS chunk q=tid (16B at tid*16, linear dest).
    // chunk q holds row r=q>>2, k-chunk (q&3)^((r>>1)&3)  [swizzle v2]
    const int r1  = tid >> 2;                               // 0..127
    const int cse = (((tid & 3) ^ ((tid >> 3) & 3)) << 3);  // source elem offset
    const unsigned short* ag0 = A + (row0 + r1      ) * (size_t)K + cse;
    const unsigned short* ag1 = A + (row0 + r1 + 128) * (size_t)K + cse;
    const unsigned short* bg0 = W + (col0 + r1      ) * (size_t)K + cse;
    const unsigned short* bg1 = W + (col0 + r1 + 128) * (size_t)K + cse;  // BN=256 only
    const int dst0 = tid * 16;
    const int dst1 = tid * 16 + 8192;

    // stage h=0: A half0 + B half0 ; h=1: A half1 (+ B half1 if BN==256)
    auto stage = [&](int h, int s, int kt) {
        if (h == 0) {
            gl_lds16(ag0 + (size_t)kt * 32, sA + s * 16384 + dst0);
            gl_lds16(bg0 + (size_t)kt * 32, sB + s * BSLOT + dst0);
        } else {
            gl_lds16(ag1 + (size_t)kt * 32, sA + s * 16384 + dst1);
            if (BN == 256)
                gl_lds16(bg1 + (size_t)kt * 32, sB + s * BSLOT + dst1);
        }
    };

    // fragment reads: addr = row*64 + ((kchunk ^ ((row>>1)&3))*16)
    const int ln15 = lane & 15;
    const int xoff = (((lane >> 4) ^ ((lane >> 1) & 3)) << 4);   // bytes
    const int arow = wr * 128 + ln15;                            // + mi*16
    const int brow = wc * (BN / 4) + ln15;                       // + nf*16

    f32x4 acc[8][NI] = {};

    // prologue: stage tile 0 into slot 0
    stage(0, 0, 0);
    stage(1, 0, 0);

#define LDA(X)  (*(const bf16x8*)(cA + (arow + (X)) * 64 + xoff))
#define LDB(X)  (*(const bf16x8*)(cB + (brow + (X)) * 64 + xoff))
#define MM(mi, af) \
    _Pragma("unroll") \
    for (int nf = 0; nf < NI; ++nf) \
        acc[mi][nf] = __builtin_amdgcn_mfma_f32_16x16x32_bf16(af, bF[nf], acc[mi][nf], 0, 0, 0);

    for (int k = 0; k < NT; ++k) {
        const char* cA = sA + (k & 1) * 16384;
        const char* cB = sB + (k & 1) * BSLOT;

        // tile top: own stage loads (issued during tile k-1) landed; then sync.
        WAITVM(0);
        SBAR();

        bf16x8 bF[NI];
        bf16x8 a0 = LDA(0),  a1 = LDA(16);
#pragma unroll
        for (int nf = 0; nf < NI; ++nf) bF[nf] = LDB(nf * 16);
        bf16x8 a2 = LDA(32), a3 = LDA(48);
        if (k + 1 < NT) stage(0, (k + 1) & 1, k + 1);
        WAITLG(2);                       // certify a0,a1,bF ; a2,a3 in flight
        __builtin_amdgcn_s_setprio(1);
        MM(0, a0) MM(1, a1)
        __builtin_amdgcn_s_setprio(0);

        bf16x8 a4 = LDA(64), a5 = LDA(80);
        WAITLG(2);                       // certify a2,a3 ; a4,a5 in flight
        __builtin_amdgcn_s_setprio(1);
        MM(2, a2) MM(3, a3)
        __builtin_amdgcn_s_setprio(0);

        bf16x8 a6 = LDA(96), a7 = LDA(112);
        if (k + 1 < NT) stage(1, (k + 1) & 1, k + 1);
        WAITLG(2);                       // certify a4,a5 ; a6,a7 in flight
        __builtin_amdgcn_s_setprio(1);
        MM(4, a4) MM(5, a5)
        __builtin_amdgcn_s_setprio(0);

        WAITLG(0);                       // certify a6,a7
        __builtin_amdgcn_s_setprio(1);
        MM(6, a6) MM(7, a7)
        __builtin_amdgcn_s_setprio(0);
    }
#undef LDA
#undef LDB
#undef MM

    // epilogue: D layout col = lane&15, row = (lane>>4)*4 + reg
    const int lq = lane >> 4;
    if (EPI == 2) {
        float bv[NI];
#pragma unroll
        for (int nf = 0; nf < NI; ++nf) bv[nf] = bias[col0 + wc * (BN / 4) + nf * 16 + ln15];
        const bool odd = (ln15 & 1);
#pragma unroll
        for (int nf = 0; nf < NI; ++nf) {
            const size_t col = col0 + wc * (BN / 4) + nf * 16 + ln15;
#pragma unroll
            for (int mi = 0; mi < 8; ++mi) {
#pragma unroll
                for (int r = 0; r < 4; ++r) {
                    const size_t row = row0 + wr * 128 + mi * 16 + lq * 4 + r;
                    float v = acc[mi][nf][r] + bv[nf];           // even lane: s, odd: t
                    float partner = __shfl_xor(v, 1, 64);
                    float zv = zin[row * N + col];
                    float res = odd ? (zv * __expf(partner) + v) : zv;
                    outf[row * N + col] = res;
                }
            }
        }
        // log_det partials: sum of s (even-lane v) per row
#pragma unroll
        for (int mi = 0; mi < 8; ++mi) {
#pragma unroll
            for (int r = 0; r < 4; ++r) {
                float sv = 0.f;
#pragma unroll
                for (int nf = 0; nf < NI; ++nf) sv += acc[mi][nf][r] + bv[nf];
                sv = odd ? 0.f : sv;
#pragma unroll
                for (int off = 1; off < 16; off <<= 1) sv += __shfl_xor(sv, off, 64);
                if (ln15 == 0) {
                    const size_t row = row0 + wr * 128 + mi * 16 + lq * 4 + r;
                    atomicAdd(&ldout[row], sv);
                }
            }
        }
    } else {
#pragma unroll
        for (int nf = 0; nf < NI; ++nf) {
            const size_t col = col0 + wc * (BN / 4) + nf * 16 + ln15;
            const float bv = bias[col];
#pragma unroll
            for (int mi = 0; mi < 8; ++mi) {
#pragma unroll
                for (int r = 0; r < 4; ++r) {
                    const size_t row = row0 + wr * 128 + mi * 16 + lq * 4 + r;
                    float v = acc[mi][nf][r] + bv;
                    if (EPI == 0) {
                        float g = 0.5f * v * (1.0f + erff(v * 0.70710678118654752f));
                        outb[row * N + col] = f2bf(g);
                    } else {
                        outf[row * N + col] = v;
                    }
                }
            }
        }
    }
}

__global__ void cvt_bf16(const float* __restrict__ in, unsigned short* __restrict__ out, int n4) {
    const int stride = gridDim.x * blockDim.x;
    for (int i = blockIdx.x * blockDim.x + threadIdx.x; i < n4; i += stride) {
        float4 v = ((const float4*)in)[i];
        us4 o{ f2bf(v.x), f2bf(v.y), f2bf(v.z), f2bf(v.w) };
        ((us4*)out)[i] = o;
    }
}

// W3 interleaved convert: out row c (0..1023) = W3 row (c&1 ? 512+(c>>1) : c>>1)
__global__ void cvt_w3i(const float* __restrict__ in, unsigned short* __restrict__ out, int n4) {
    const int stride = gridDim.x * blockDim.x;
    for (int i = blockIdx.x * blockDim.x + threadIdx.x; i < n4; i += stride) {
        int row = i >> 9;           // 512 float4 per 2048-col row
        int c4  = i & 511;
        int srcrow = (row & 1) ? 512 + (row >> 1) : (row >> 1);
        float4 v = ((const float4*)in)[srcrow * 512 + c4];
        us4 o{ f2bf(v.x), f2bf(v.y), f2bf(v.z), f2bf(v.w) };
        ((us4*)out)[i] = o;
    }
}

// zm[row][i] = bf16(z[row][2i])
__global__ void pack_even(const float* __restrict__ z, unsigned short* __restrict__ zm, int n4) {
    const int stride = gridDim.x * blockDim.x;
    for (int i = blockIdx.x * blockDim.x + threadIdx.x; i < n4; i += stride) {
        float4 v = ((const float4*)z)[i];
        us2 o{ f2bf(v.x), f2bf(v.z) };
        ((us2*)zm)[i] = o;
    }
}

// b3 interleave + ldout init
__global__ void prep3(const float* __restrict__ b3, float* __restrict__ b3i,
                      const float* __restrict__ ld, float* __restrict__ ldout, int nrow) {
    const int stride = gridDim.x * blockDim.x;
    int i = blockIdx.x * blockDim.x + threadIdx.x;
    if (i < 1024) b3i[i] = b3[(i & 1) ? 512 + (i >> 1) : (i >> 1)];
    for (int r = i; r < nrow; r += stride) ldout[r] = ld[r];
}

extern "C" void kernel_launch(void* const* d_in, const int* in_sizes, int n_in,
                              void* d_out, int out_size, void* d_ws, size_t ws_size,
                              hipStream_t stream)
{
    const float* z  = (const float*)d_in[0];
    const float* ld = (const float*)d_in[1];
    const float* W1 = (const float*)d_in[2];
    const float* b1 = (const float*)d_in[3];
    const float* W2 = (const float*)d_in[4];
    const float* b2 = (const float*)d_in[5];
    const float* W3 = (const float*)d_in[6];
    const float* b3 = (const float*)d_in[7];

    float* out   = (float*)d_out;
    float* zout  = out;
    float* ldout = out + (size_t)16384 * 1024;

    char* w = (char*)d_ws;
    unsigned short* zm  = (unsigned short*)w; w += (size_t)16384 * 512 * 2;
    unsigned short* w1b = (unsigned short*)w; w += (size_t)2048 * 512 * 2;
    unsigned short* w2b = (unsigned short*)w; w += (size_t)2048 * 2048 * 2;
    unsigned short* w3i = (unsigned short*)w; w += (size_t)1024 * 2048 * 2;
    unsigned short* h1  = (unsigned short*)w; w += (size_t)16384 * 2048 * 2;
    unsigned short* h2  = (unsigned short*)w; w += (size_t)16384 * 2048 * 2;
    float*          b3i = (float*)w;          w += 1024 * 4;

    (void)hipFuncSetAttribute((const void*)&gemm256<0, 512,  2048, 256>,
                              hipFuncAttributeMaxDynamicSharedMemorySize, 65536);
    (void)hipFuncSetAttribute((const void*)&gemm256<0, 2048, 2048, 256>,
                              hipFuncAttributeMaxDynamicSharedMemorySize, 65536);
    (void)hipFuncSetAttribute((const void*)&gemm256<2, 2048, 1024, 128>,
                              hipFuncAttributeMaxDynamicSharedMemorySize, 49152);

    cvt_bf16 <<<512,  256, 0, stream>>>(W1, w1b, 2048 * 512 / 4);
    cvt_bf16 <<<2048, 256, 0, stream>>>(W2, w2b, 2048 * 2048 / 4);
    cvt_w3i  <<<1024, 256, 0, stream>>>(W3, w3i, 1024 * 2048 / 4);
    pack_even<<<2048, 256, 0, stream>>>(z, zm, 16384 * 1024 / 4);
    prep3    <<<64,   256, 0, stream>>>(b3, b3i, ld, ldout, 16384);

    gemm256<0, 512,  2048, 256><<<dim3(8, 64), 512, 65536, stream>>>(zm, w1b, b1, h1, nullptr, nullptr, nullptr);
    gemm256<0, 2048, 2048, 256><<<dim3(8, 64), 512, 65536, stream>>>(h1, w2b, b2, h2, nullptr, nullptr, nullptr);
    gemm256<2, 2048, 1024, 128><<<dim3(8, 64), 512, 49152, stream>>>(h2, w3i, b3i, nullptr, zout, z, ldout);
}

// Round 7
// 369.112 us; speedup vs baseline: 3.7336x; 3.7336x over previous
//
#include <hip/hip_runtime.h>
#include <hip/hip_bf16.h>
#include <cstdint>

typedef __bf16 bf16x8 __attribute__((ext_vector_type(8)));
typedef float  f32x4  __attribute__((ext_vector_type(4)));

struct alignas(4) us2 { unsigned short x, y; };
struct alignas(8) us4 { unsigned short x, y, z, w; };

__device__ __forceinline__ unsigned short f2bf(float f) {
    union { float f; unsigned u; } a; a.f = f;
    unsigned r = a.u + 0x7fffu + ((a.u >> 16) & 1u);   // round-to-nearest-even
    return (unsigned short)(r >> 16);
}

__device__ __forceinline__ void gl_lds16(const void* g, void* s) {
    __builtin_amdgcn_global_load_lds(
        (const __attribute__((address_space(1))) void*)g,
        (__attribute__((address_space(3))) void*)s, 16, 0, 0);
}

#define SCHEDB()  __builtin_amdgcn_sched_barrier(0)
#define SBAR()    do { SCHEDB(); __builtin_amdgcn_s_barrier(); SCHEDB(); } while (0)
#define WAITLG(N) do { asm volatile("s_waitcnt lgkmcnt(" #N ")" ::: "memory"); SCHEDB(); } while (0)
#define WAITVM(N) do { asm volatile("s_waitcnt vmcnt(" #N ")" ::: "memory"); SCHEDB(); } while (0)

// C = A(MxK) @ W(NxK)^T, bf16 in, fp32 acc. 256x256 tile, BK=64, 8 waves (2Mx4N),
// 2-slot double-buffered LDS (2 x 64KB = 128KB), 1 block/CU (m201 geometry).
// Per K-tile: 3 phases {16,16,32} MFMA. All 8 stage-loads for tile t+1 issued in
// phase 0 of tile t (~3 phases of slack -> tile-top vmcnt(0) is stale/cheap).
// ds_reads issued one phase ahead of use, certified by counted lgkmcnt; group
// order pinned by sched_barrier(0). Swizzle v3 for 128B row stride:
// stored chunk pos = src_chunk ^ (row&7)  -> exact 8-accesses-per-bank balance.
// EPI 0: outb = bf16(gelu_exact(acc+bias)) ; EPI 1: outf = acc+bias ;
// EPI 2: fused coupling (W interleaved s/t): even col -> s, odd -> t.
template<int EPI, int K, int N>
__global__ __launch_bounds__(512, 2)
void gemm256(const unsigned short* __restrict__ A,
             const unsigned short* __restrict__ W,
             const float* __restrict__ bias,
             unsigned short* __restrict__ outb,
             float* __restrict__ outf,
             const float* __restrict__ zin,
             float* __restrict__ ldout)
{
    extern __shared__ char smem[];
    constexpr int NT = K / 64;
    constexpr int GX = N / 256;

    const int tid  = threadIdx.x;
    const int lane = tid & 63;
    const int wv   = tid >> 6;           // 0..7
    const int wr   = wv >> 2, wc = wv & 3;

    // T1: bijective XCD swizzle (nwg divisible by 8 for all our shapes)
    const int bid = blockIdx.y * GX + blockIdx.x;
    const int nwg = GX * (int)gridDim.y;
    const int swz = (bid & 7) * (nwg >> 3) + (bid >> 3);
    const size_t row0 = (size_t)(swz / GX) * 256;
    const size_t col0 = (size_t)(swz % GX) * 256;

    // LDS: slot s at smem + s*65536 ; A tile (256 rows x 128B) at +0, B at +32768.
    // Staging: thread tid writes chunks q2 = j*512 + tid (j=0..3) at byte q2*16.
    // Chunk q2: row = q2>>3, pos = q2&7, holds src k-chunk pos ^ (row&7).
    const int r0  = tid >> 3;                               // 0..63
    const int cse = (((tid & 7) ^ ((tid >> 3) & 7)) << 3);  // src elem offset (0..56)
    const unsigned short* ag = A + (row0 + r0) * (size_t)K + cse;
    const unsigned short* bg = W + (col0 + r0) * (size_t)K + cse;

    auto stage_tile = [&](int tt) {
        char* dstA = smem + (tt & 1) * 65536 + tid * 16;
        char* dstB = dstA + 32768;
        const size_t ko = (size_t)tt * 64;
#pragma unroll
        for (int j = 0; j < 4; ++j) {
            gl_lds16(ag + ((size_t)j * 64) * K + ko, dstA + j * 8192);
            gl_lds16(bg + ((size_t)j * 64) * K + ko, dstB + j * 8192);
        }
    };

    // fragment reads: byte = row*128 + (((kk<<2)|q3) ^ (row&7))*16, row&7 == ln15&7
    const int ln15 = lane & 15;
    const int xo   = (((lane >> 4) ^ (ln15 & 7)) << 4);     // kk=0 ; kk=1: ^64
    const int arow = wr * 128 + ln15;                       // + mi*16 (mi 0..7)
    const int brow = wc * 64 + ln15;                        // + nf*16 (nf 0..3)

#define LD(base, row, kk) (*(const bf16x8*)((base) + (row) * 128 + (xo ^ ((kk) << 6))))

    f32x4 acc[8][4] = {};

    stage_tile(0);

    for (int t = 0; t < NT; ++t) {
        const char* cA = smem + (t & 1) * 65536;
        const char* cB = cA + 32768;

        WAITVM(0);          // certify tile t (staged in phase 0 of t-1; stale)
        SBAR();

        bf16x8 aL[8], bL[4], bH[4], aH[8];
        // ---- P0 reads: aLo(8) + bLo(4), then bHi(4) [order pinned] ----
#pragma unroll
        for (int mf = 0; mf < 4; ++mf) {
            aL[2 * mf]     = LD(cA, arow + mf * 16, 0);
            aL[2 * mf + 1] = LD(cA, arow + mf * 16, 1);
        }
#pragma unroll
        for (int nf = 0; nf < 2; ++nf) {
            bL[2 * nf]     = LD(cB, brow + nf * 16, 0);
            bL[2 * nf + 1] = LD(cB, brow + nf * 16, 1);
        }
        SCHEDB();
#pragma unroll
        for (int nf = 0; nf < 2; ++nf) {
            bH[2 * nf]     = LD(cB, brow + (nf + 2) * 16, 0);
            bH[2 * nf + 1] = LD(cB, brow + (nf + 2) * 16, 1);
        }
        if (t + 1 < NT) stage_tile(t + 1);   // all 8 vmem for next tile, early
        WAITLG(4);                            // aLo+bLo ready; bHi may float
        __builtin_amdgcn_s_setprio(1);
#pragma unroll
        for (int mf = 0; mf < 4; ++mf)
#pragma unroll
            for (int nf = 0; nf < 2; ++nf) {
                acc[mf][nf] = __builtin_amdgcn_mfma_f32_16x16x32_bf16(aL[2*mf],   bL[2*nf],   acc[mf][nf], 0, 0, 0);
                acc[mf][nf] = __builtin_amdgcn_mfma_f32_16x16x32_bf16(aL[2*mf+1], bL[2*nf+1], acc[mf][nf], 0, 0, 0);
            }
        __builtin_amdgcn_s_setprio(0);
        SBAR();

        // ---- P1: issue aHi(8) for P2/3 ; compute aLo x bHi ----
#pragma unroll
        for (int mf = 0; mf < 4; ++mf) {
            aH[2 * mf]     = LD(cA, arow + 64 + mf * 16, 0);
            aH[2 * mf + 1] = LD(cA, arow + 64 + mf * 16, 1);
        }
        WAITLG(8);                            // bHi ready; aHi may float
        __builtin_amdgcn_s_setprio(1);
#pragma unroll
        for (int mf = 0; mf < 4; ++mf)
#pragma unroll
            for (int nf = 0; nf < 2; ++nf) {
                acc[mf][nf+2] = __builtin_amdgcn_mfma_f32_16x16x32_bf16(aL[2*mf],   bH[2*nf],   acc[mf][nf+2], 0, 0, 0);
                acc[mf][nf+2] = __builtin_amdgcn_mfma_f32_16x16x32_bf16(aL[2*mf+1], bH[2*nf+1], acc[mf][nf+2], 0, 0, 0);
            }
        __builtin_amdgcn_s_setprio(0);
        SBAR();

        // ---- P2+P3: aHi x (bLo,bHi) = 32 MFMA ----
        WAITLG(0);
        __builtin_amdgcn_s_setprio(1);
#pragma unroll
        for (int mf = 0; mf < 4; ++mf)
#pragma unroll
            for (int nf = 0; nf < 2; ++nf) {
                acc[mf+4][nf]   = __builtin_amdgcn_mfma_f32_16x16x32_bf16(aH[2*mf],   bL[2*nf],   acc[mf+4][nf],   0, 0, 0);
                acc[mf+4][nf]   = __builtin_amdgcn_mfma_f32_16x16x32_bf16(aH[2*mf+1], bL[2*nf+1], acc[mf+4][nf],   0, 0, 0);
                acc[mf+4][nf+2] = __builtin_amdgcn_mfma_f32_16x16x32_bf16(aH[2*mf],   bH[2*nf],   acc[mf+4][nf+2], 0, 0, 0);
                acc[mf+4][nf+2] = __builtin_amdgcn_mfma_f32_16x16x32_bf16(aH[2*mf+1], bH[2*nf+1], acc[mf+4][nf+2], 0, 0, 0);
            }
        __builtin_amdgcn_s_setprio(0);
    }
#undef LD

    // epilogue: D layout col = lane&15, row = (lane>>4)*4 + reg
    const int lq = lane >> 4;
    if (EPI == 2) {
        float bv[4];
#pragma unroll
        for (int nf = 0; nf < 4; ++nf) bv[nf] = bias[col0 + wc * 64 + nf * 16 + ln15];
        const bool odd = (ln15 & 1);
#pragma unroll
        for (int nf = 0; nf < 4; ++nf) {
            const size_t col = col0 + wc * 64 + nf * 16 + ln15;
#pragma unroll
            for (int mi = 0; mi < 8; ++mi) {
#pragma unroll
                for (int r = 0; r < 4; ++r) {
                    const size_t row = row0 + wr * 128 + mi * 16 + lq * 4 + r;
                    float v = acc[mi][nf][r] + bv[nf];           // even lane: s, odd: t
                    float partner = __shfl_xor(v, 1, 64);
                    float zv = zin[row * N + col];
                    float res = odd ? (zv * __expf(partner) + v) : zv;
                    outf[row * N + col] = res;
                }
            }
        }
        // log_det partials: sum of s (even-lane v) per row
#pragma unroll
        for (int mi = 0; mi < 8; ++mi) {
#pragma unroll
            for (int r = 0; r < 4; ++r) {
                float sv = 0.f;
#pragma unroll
                for (int nf = 0; nf < 4; ++nf) sv += acc[mi][nf][r] + bv[nf];
                sv = odd ? 0.f : sv;
#pragma unroll
                for (int off = 1; off < 16; off <<= 1) sv += __shfl_xor(sv, off, 64);
                if (ln15 == 0) {
                    const size_t row = row0 + wr * 128 + mi * 16 + lq * 4 + r;
                    atomicAdd(&ldout[row], sv);
                }
            }
        }
    } else {
#pragma unroll
        for (int nf = 0; nf < 4; ++nf) {
            const size_t col = col0 + wc * 64 + nf * 16 + ln15;
            const float bv = bias[col];
#pragma unroll
            for (int mi = 0; mi < 8; ++mi) {
#pragma unroll
                for (int r = 0; r < 4; ++r) {
                    const size_t row = row0 + wr * 128 + mi * 16 + lq * 4 + r;
                    float v = acc[mi][nf][r] + bv;
                    if (EPI == 0) {
                        float g = 0.5f * v * (1.0f + erff(v * 0.70710678118654752f));
                        outb[row * N + col] = f2bf(g);
                    } else {
                        outf[row * N + col] = v;
                    }
                }
            }
        }
    }
}

__global__ void cvt_bf16(const float* __restrict__ in, unsigned short* __restrict__ out, int n4) {
    const int stride = gridDim.x * blockDim.x;
    for (int i = blockIdx.x * blockDim.x + threadIdx.x; i < n4; i += stride) {
        float4 v = ((const float4*)in)[i];
        us4 o{ f2bf(v.x), f2bf(v.y), f2bf(v.z), f2bf(v.w) };
        ((us4*)out)[i] = o;
    }
}

// W3 interleaved convert: out row c (0..1023) = W3 row (c&1 ? 512+(c>>1) : c>>1)
__global__ void cvt_w3i(const float* __restrict__ in, unsigned short* __restrict__ out, int n4) {
    const int stride = gridDim.x * blockDim.x;
    for (int i = blockIdx.x * blockDim.x + threadIdx.x; i < n4; i += stride) {
        int row = i >> 9;           // 512 float4 per 2048-col row
        int c4  = i & 511;
        int srcrow = (row & 1) ? 512 + (row >> 1) : (row >> 1);
        float4 v = ((const float4*)in)[srcrow * 512 + c4];
        us4 o{ f2bf(v.x), f2bf(v.y), f2bf(v.z), f2bf(v.w) };
        ((us4*)out)[i] = o;
    }
}

// zm[row][i] = bf16(z[row][2i])
__global__ void pack_even(const float* __restrict__ z, unsigned short* __restrict__ zm, int n4) {
    const int stride = gridDim.x * blockDim.x;
    for (int i = blockIdx.x * blockDim.x + threadIdx.x; i < n4; i += stride) {
        float4 v = ((const float4*)z)[i];
        us2 o{ f2bf(v.x), f2bf(v.z) };
        ((us2*)zm)[i] = o;
    }
}

// b3 interleave + ldout init
__global__ void prep3(const float* __restrict__ b3, float* __restrict__ b3i,
                      const float* __restrict__ ld, float* __restrict__ ldout, int nrow) {
    const int stride = gridDim.x * blockDim.x;
    int i = blockIdx.x * blockDim.x + threadIdx.x;
    if (i < 1024) b3i[i] = b3[(i & 1) ? 512 + (i >> 1) : (i >> 1)];
    for (int r = i; r < nrow; r += stride) ldout[r] = ld[r];
}

extern "C" void kernel_launch(void* const* d_in, const int* in_sizes, int n_in,
                              void* d_out, int out_size, void* d_ws, size_t ws_size,
                              hipStream_t stream)
{
    const float* z  = (const float*)d_in[0];
    const float* ld = (const float*)d_in[1];
    const float* W1 = (const float*)d_in[2];
    const float* b1 = (const float*)d_in[3];
    const float* W2 = (const float*)d_in[4];
    const float* b2 = (const float*)d_in[5];
    const float* W3 = (const float*)d_in[6];
    const float* b3 = (const float*)d_in[7];

    float* out   = (float*)d_out;
    float* zout  = out;
    float* ldout = out + (size_t)16384 * 1024;

    char* w = (char*)d_ws;
    unsigned short* zm  = (unsigned short*)w; w += (size_t)16384 * 512 * 2;
    unsigned short* w1b = (unsigned short*)w; w += (size_t)2048 * 512 * 2;
    unsigned short* w2b = (unsigned short*)w; w += (size_t)2048 * 2048 * 2;
    unsigned short* w3i = (unsigned short*)w; w += (size_t)1024 * 2048 * 2;
    unsigned short* h1  = (unsigned short*)w; w += (size_t)16384 * 2048 * 2;
    unsigned short* h2  = (unsigned short*)w; w += (size_t)16384 * 2048 * 2;
    float*          b3i = (float*)w;          w += 1024 * 4;

    (void)hipFuncSetAttribute((const void*)&gemm256<0, 512,  2048>,
                              hipFuncAttributeMaxDynamicSharedMemorySize, 131072);
    (void)hipFuncSetAttribute((const void*)&gemm256<0, 2048, 2048>,
                              hipFuncAttributeMaxDynamicSharedMemorySize, 131072);
    (void)hipFuncSetAttribute((const void*)&gemm256<2, 2048, 1024>,
                              hipFuncAttributeMaxDynamicSharedMemorySize, 131072);

    cvt_bf16 <<<512,  256, 0, stream>>>(W1, w1b, 2048 * 512 / 4);
    cvt_bf16 <<<2048, 256, 0, stream>>>(W2, w2b, 2048 * 2048 / 4);
    cvt_w3i  <<<1024, 256, 0, stream>>>(W3, w3i, 1024 * 2048 / 4);
    pack_even<<<2048, 256, 0, stream>>>(z, zm, 16384 * 1024 / 4);
    prep3    <<<64,   256, 0, stream>>>(b3, b3i, ld, ldout, 16384);

    gemm256<0, 512,  2048><<<dim3(8, 64), 512, 131072, stream>>>(zm, w1b, b1, h1, nullptr, nullptr, nullptr);
    gemm256<0, 2048, 2048><<<dim3(8, 64), 512, 131072, stream>>>(h1, w2b, b2, h2, nullptr, nullptr, nullptr);
    gemm256<2, 2048, 1024><<<dim3(4, 64), 512, 131072, stream>>>(h2, w3i, b3i, nullptr, zout, z, ldout);
}

// Round 8
// 365.148 us; speedup vs baseline: 3.7741x; 1.0109x over previous
//
#include <hip/hip_runtime.h>
#include <hip/hip_bf16.h>
#include <cstdint>

typedef __bf16 bf16x8 __attribute__((ext_vector_type(8)));
typedef float  f32x4  __attribute__((ext_vector_type(4)));

struct alignas(4) us2 { unsigned short x, y; };
struct alignas(8) us4 { unsigned short x, y, z, w; };

__device__ __forceinline__ unsigned short f2bf(float f) {
    union { float f; unsigned u; } a; a.f = f;
    unsigned r = a.u + 0x7fffu + ((a.u >> 16) & 1u);   // round-to-nearest-even
    return (unsigned short)(r >> 16);
}

__device__ __forceinline__ void gl_lds16(const void* g, void* s) {
    __builtin_amdgcn_global_load_lds(
        (const __attribute__((address_space(1))) void*)g,
        (__attribute__((address_space(3))) void*)s, 16, 0, 0);
}

#define SCHEDB()  __builtin_amdgcn_sched_barrier(0)
#define SBAR()    do { SCHEDB(); __builtin_amdgcn_s_barrier(); SCHEDB(); } while (0)
#define WAITLG(N) do { asm volatile("s_waitcnt lgkmcnt(" #N ")" ::: "memory"); SCHEDB(); } while (0)
#define WAITVM(N) do { asm volatile("s_waitcnt vmcnt(" #N ")" ::: "memory"); SCHEDB(); } while (0)

// C = A(MxK) @ W(NxK)^T, bf16 in, fp32 acc. 256x256 tile, BK=64, 8 waves (2Mx4N),
// 2-slot double-buffered LDS (2 x 64KB), 1 block/CU. m201 4-phase schedule:
// per phase: {ds_reads -> 2-4 stage gl_lds -> [lgkm throttle] -> BARRIER ->
// lgkmcnt(0) -> setprio(1) -> 16 MFMA (kk-outer, no acc chaining) -> setprio(0)
// -> BARRIER}. Read latency is absorbed by the barrier (issue before, certify
// after). vmcnt(0)+barrier once per tile at phase-4 end (loads >=2 phases old).
// Swizzle v3 (0 conflicts): stored chunk pos = src_chunk ^ (row&7).
// EPI 0: outb = bf16(gelu_exact(acc+bias)) ; EPI 1: outf = acc+bias ;
// EPI 2: fused coupling (W interleaved s/t): even col -> s, odd -> t.
template<int EPI, int K, int N>
__global__ __launch_bounds__(512, 2)
void gemm256(const unsigned short* __restrict__ A,
             const unsigned short* __restrict__ W,
             const float* __restrict__ bias,
             unsigned short* __restrict__ outb,
             float* __restrict__ outf,
             const float* __restrict__ zin,
             float* __restrict__ ldout)
{
    extern __shared__ char smem[];
    constexpr int NT = K / 64;
    constexpr int GX = N / 256;

    const int tid  = threadIdx.x;
    const int lane = tid & 63;
    const int wv   = tid >> 6;           // 0..7
    const int wr   = wv >> 2, wc = wv & 3;

    // T1: bijective XCD swizzle (nwg divisible by 8 for all our shapes)
    const int bid = blockIdx.y * GX + blockIdx.x;
    const int nwg = GX * (int)gridDim.y;
    const int swz = (bid & 7) * (nwg >> 3) + (bid >> 3);
    const size_t row0 = (size_t)(swz / GX) * 256;
    const size_t col0 = (size_t)(swz % GX) * 256;

    // LDS slot s at smem + s*65536 ; A tile (256 x 128B) at +0, B at +32768.
    // Staging: thread tid writes chunks q2 = j*512 + tid at byte q2*16.
    // Chunk q2: row = q2>>3, pos = q2&7, holds src k-chunk pos ^ (row&7).
    const int r0  = tid >> 3;                               // 0..63
    const int cse = (((tid & 7) ^ ((tid >> 3) & 7)) << 3);  // src elem offset
    const unsigned short* ag = A + (row0 + r0) * (size_t)K + cse;
    const unsigned short* bg = W + (col0 + r0) * (size_t)K + cse;

    auto stage_a = [&](int tt) {   // A rows j=0,1 + B rows j=0,1 (4 loads)
        char* dstA = smem + (tt & 1) * 65536 + tid * 16;
        char* dstB = dstA + 32768;
        const size_t ko = (size_t)tt * 64;
        gl_lds16(ag + ko,                       dstA);
        gl_lds16(ag + (size_t)64 * K + ko,      dstA + 8192);
        gl_lds16(bg + ko,                       dstB);
        gl_lds16(bg + (size_t)64 * K + ko,      dstB + 8192);
    };
    auto stage_b = [&](int tt) {   // A rows j=2,3 + B rows j=2,3 (4 loads)
        char* dstA = smem + (tt & 1) * 65536 + tid * 16;
        char* dstB = dstA + 32768;
        const size_t ko = (size_t)tt * 64;
        gl_lds16(ag + (size_t)128 * K + ko,     dstA + 16384);
        gl_lds16(ag + (size_t)192 * K + ko,     dstA + 24576);
        gl_lds16(bg + (size_t)128 * K + ko,     dstB + 16384);
        gl_lds16(bg + (size_t)192 * K + ko,     dstB + 24576);
    };

    // fragment reads: byte = row*128 + (((kk<<2)|q) ^ (row&7))*16
    const int ln15 = lane & 15;
    const int xo   = (((lane >> 4) ^ (ln15 & 7)) << 4);     // kk=0 ; kk=1: ^64
    const int arow = wr * 128 + ln15;                       // + mi*16
    const int brow = wc * 64 + ln15;                        // + nf*16

#define LD(base, row, kk) (*(const bf16x8*)((base) + (row) * 128 + (xo ^ ((kk) << 6))))

    f32x4 acc[8][4] = {};

    stage_a(0);
    stage_b(0);
    WAITVM(0);
    SBAR();

    for (int t = 0; t < NT; ++t) {
        const char* cA = smem + (t & 1) * 65536;
        const char* cB = cA + 32768;
        bf16x8 aL[8], aH[8], bL[4], bH[4];

        // ===== phase 1: read A-lo(8)+B-lo(4); stage 4; MFMA m-lo x n-lo =====
#pragma unroll
        for (int mf = 0; mf < 4; ++mf) {
            aL[2 * mf]     = LD(cA, arow + mf * 16, 0);
            aL[2 * mf + 1] = LD(cA, arow + mf * 16, 1);
        }
#pragma unroll
        for (int nf = 0; nf < 2; ++nf) {
            bL[2 * nf]     = LD(cB, brow + nf * 16, 0);
            bL[2 * nf + 1] = LD(cB, brow + nf * 16, 1);
        }
        if (t + 1 < NT) stage_a(t + 1);
        WAITLG(8);
        SBAR();
        WAITLG(0);
        __builtin_amdgcn_s_setprio(1);
#pragma unroll
        for (int kk = 0; kk < 2; ++kk)
#pragma unroll
            for (int mf = 0; mf < 4; ++mf)
#pragma unroll
                for (int nf = 0; nf < 2; ++nf)
                    acc[mf][nf] = __builtin_amdgcn_mfma_f32_16x16x32_bf16(
                        aL[2 * mf + kk], bL[2 * nf + kk], acc[mf][nf], 0, 0, 0);
        __builtin_amdgcn_s_setprio(0);
        SBAR();

        // ===== phase 2: read B-hi(4); stage 4; MFMA m-lo x n-hi =====
#pragma unroll
        for (int nf = 0; nf < 2; ++nf) {
            bH[2 * nf]     = LD(cB, brow + (nf + 2) * 16, 0);
            bH[2 * nf + 1] = LD(cB, brow + (nf + 2) * 16, 1);
        }
        if (t + 1 < NT) stage_b(t + 1);
        SBAR();
        WAITLG(0);
        __builtin_amdgcn_s_setprio(1);
#pragma unroll
        for (int kk = 0; kk < 2; ++kk)
#pragma unroll
            for (int mf = 0; mf < 4; ++mf)
#pragma unroll
                for (int nf = 0; nf < 2; ++nf)
                    acc[mf][nf + 2] = __builtin_amdgcn_mfma_f32_16x16x32_bf16(
                        aL[2 * mf + kk], bH[2 * nf + kk], acc[mf][nf + 2], 0, 0, 0);
        __builtin_amdgcn_s_setprio(0);
        SBAR();

        // ===== phase 3: read A-hi(8); MFMA m-hi x n-hi =====
#pragma unroll
        for (int mf = 0; mf < 4; ++mf) {
            aH[2 * mf]     = LD(cA, arow + 64 + mf * 16, 0);
            aH[2 * mf + 1] = LD(cA, arow + 64 + mf * 16, 1);
        }
        SBAR();
        WAITLG(0);
        __builtin_amdgcn_s_setprio(1);
#pragma unroll
        for (int kk = 0; kk < 2; ++kk)
#pragma unroll
            for (int mf = 0; mf < 4; ++mf)
#pragma unroll
                for (int nf = 0; nf < 2; ++nf)
                    acc[mf + 4][nf + 2] = __builtin_amdgcn_mfma_f32_16x16x32_bf16(
                        aH[2 * mf + kk], bH[2 * nf + kk], acc[mf + 4][nf + 2], 0, 0, 0);
        __builtin_amdgcn_s_setprio(0);
        SBAR();

        // ===== phase 4: no reads; MFMA m-hi x n-lo; vmcnt cert + barrier =====
        __builtin_amdgcn_s_setprio(1);
#pragma unroll
        for (int kk = 0; kk < 2; ++kk)
#pragma unroll
            for (int mf = 0; mf < 4; ++mf)
#pragma unroll
                for (int nf = 0; nf < 2; ++nf)
                    acc[mf + 4][nf] = __builtin_amdgcn_mfma_f32_16x16x32_bf16(
                        aH[2 * mf + kk], bL[2 * nf + kk], acc[mf + 4][nf], 0, 0, 0);
        __builtin_amdgcn_s_setprio(0);
        WAITVM(0);       // certify tile t+1 (issued ph1/ph2, >=2 phases old)
        SBAR();
    }
#undef LD

    // epilogue: D layout col = lane&15, row = (lane>>4)*4 + reg
    const int lq = lane >> 4;
    if (EPI == 2) {
        float bv[4];
#pragma unroll
        for (int nf = 0; nf < 4; ++nf) bv[nf] = bias[col0 + wc * 64 + nf * 16 + ln15];
        const bool odd = (ln15 & 1);
#pragma unroll
        for (int nf = 0; nf < 4; ++nf) {
            const size_t col = col0 + wc * 64 + nf * 16 + ln15;
#pragma unroll
            for (int mi = 0; mi < 8; ++mi) {
#pragma unroll
                for (int r = 0; r < 4; ++r) {
                    const size_t row = row0 + wr * 128 + mi * 16 + lq * 4 + r;
                    float v = acc[mi][nf][r] + bv[nf];           // even lane: s, odd: t
                    float partner = __shfl_xor(v, 1, 64);
                    float zv = zin[row * N + col];
                    float res = odd ? (zv * __expf(partner) + v) : zv;
                    outf[row * N + col] = res;
                }
            }
        }
        // log_det partials: sum of s (even-lane v) per row
#pragma unroll
        for (int mi = 0; mi < 8; ++mi) {
#pragma unroll
            for (int r = 0; r < 4; ++r) {
                float sv = 0.f;
#pragma unroll
                for (int nf = 0; nf < 4; ++nf) sv += acc[mi][nf][r] + bv[nf];
                sv = odd ? 0.f : sv;
#pragma unroll
                for (int off = 1; off < 16; off <<= 1) sv += __shfl_xor(sv, off, 64);
                if (ln15 == 0) {
                    const size_t row = row0 + wr * 128 + mi * 16 + lq * 4 + r;
                    atomicAdd(&ldout[row], sv);
                }
            }
        }
    } else {
#pragma unroll
        for (int nf = 0; nf < 4; ++nf) {
            const size_t col = col0 + wc * 64 + nf * 16 + ln15;
            const float bv = bias[col];
#pragma unroll
            for (int mi = 0; mi < 8; ++mi) {
#pragma unroll
                for (int r = 0; r < 4; ++r) {
                    const size_t row = row0 + wr * 128 + mi * 16 + lq * 4 + r;
                    float v = acc[mi][nf][r] + bv;
                    if (EPI == 0) {
                        float g = 0.5f * v * (1.0f + erff(v * 0.70710678118654752f));
                        outb[row * N + col] = f2bf(g);
                    } else {
                        outf[row * N + col] = v;
                    }
                }
            }
        }
    }
}

__global__ void cvt_bf16(const float* __restrict__ in, unsigned short* __restrict__ out, int n4) {
    const int stride = gridDim.x * blockDim.x;
    for (int i = blockIdx.x * blockDim.x + threadIdx.x; i < n4; i += stride) {
        float4 v = ((const float4*)in)[i];
        us4 o{ f2bf(v.x), f2bf(v.y), f2bf(v.z), f2bf(v.w) };
        ((us4*)out)[i] = o;
    }
}

// W3 interleaved convert: out row c (0..1023) = W3 row (c&1 ? 512+(c>>1) : c>>1)
__global__ void cvt_w3i(const float* __restrict__ in, unsigned short* __restrict__ out, int n4) {
    const int stride = gridDim.x * blockDim.x;
    for (int i = blockIdx.x * blockDim.x + threadIdx.x; i < n4; i += stride) {
        int row = i >> 9;           // 512 float4 per 2048-col row
        int c4  = i & 511;
        int srcrow = (row & 1) ? 512 + (row >> 1) : (row >> 1);
        float4 v = ((const float4*)in)[srcrow * 512 + c4];
        us4 o{ f2bf(v.x), f2bf(v.y), f2bf(v.z), f2bf(v.w) };
        ((us4*)out)[i] = o;
    }
}

// zm[row][i] = bf16(z[row][2i])
__global__ void pack_even(const float* __restrict__ z, unsigned short* __restrict__ zm, int n4) {
    const int stride = gridDim.x * blockDim.x;
    for (int i = blockIdx.x * blockDim.x + threadIdx.x; i < n4; i += stride) {
        float4 v = ((const float4*)z)[i];
        us2 o{ f2bf(v.x), f2bf(v.z) };
        ((us2*)zm)[i] = o;
    }
}

// b3 interleave + ldout init
__global__ void prep3(const float* __restrict__ b3, float* __restrict__ b3i,
                      const float* __restrict__ ld, float* __restrict__ ldout, int nrow) {
    const int stride = gridDim.x * blockDim.x;
    int i = blockIdx.x * blockDim.x + threadIdx.x;
    if (i < 1024) b3i[i] = b3[(i & 1) ? 512 + (i >> 1) : (i >> 1)];
    for (int r = i; r < nrow; r += stride) ldout[r] = ld[r];
}

extern "C" void kernel_launch(void* const* d_in, const int* in_sizes, int n_in,
                              void* d_out, int out_size, void* d_ws, size_t ws_size,
                              hipStream_t stream)
{
    const float* z  = (const float*)d_in[0];
    const float* ld = (const float*)d_in[1];
    const float* W1 = (const float*)d_in[2];
    const float* b1 = (const float*)d_in[3];
    const float* W2 = (const float*)d_in[4];
    const float* b2 = (const float*)d_in[5];
    const float* W3 = (const float*)d_in[6];
    const float* b3 = (const float*)d_in[7];

    float* out   = (float*)d_out;
    float* zout  = out;
    float* ldout = out + (size_t)16384 * 1024;

    char* w = (char*)d_ws;
    unsigned short* zm  = (unsigned short*)w; w += (size_t)16384 * 512 * 2;
    unsigned short* w1b = (unsigned short*)w; w += (size_t)2048 * 512 * 2;
    unsigned short* w2b = (unsigned short*)w; w += (size_t)2048 * 2048 * 2;
    unsigned short* w3i = (unsigned short*)w; w += (size_t)1024 * 2048 * 2;
    unsigned short* h1  = (unsigned short*)w; w += (size_t)16384 * 2048 * 2;
    unsigned short* h2  = (unsigned short*)w; w += (size_t)16384 * 2048 * 2;
    float*          b3i = (float*)w;          w += 1024 * 4;

    (void)hipFuncSetAttribute((const void*)&gemm256<0, 512,  2048>,
                              hipFuncAttributeMaxDynamicSharedMemorySize, 131072);
    (void)hipFuncSetAttribute((const void*)&gemm256<0, 2048, 2048>,
                              hipFuncAttributeMaxDynamicSharedMemorySize, 131072);
    (void)hipFuncSetAttribute((const void*)&gemm256<2, 2048, 1024>,
                              hipFuncAttributeMaxDynamicSharedMemorySize, 131072);

    cvt_bf16 <<<512,  256, 0, stream>>>(W1, w1b, 2048 * 512 / 4);
    cvt_bf16 <<<2048, 256, 0, stream>>>(W2, w2b, 2048 * 2048 / 4);
    cvt_w3i  <<<1024, 256, 0, stream>>>(W3, w3i, 1024 * 2048 / 4);
    pack_even<<<2048, 256, 0, stream>>>(z, zm, 16384 * 1024 / 4);
    prep3    <<<64,   256, 0, stream>>>(b3, b3i, ld, ldout, 16384);

    gemm256<0, 512,  2048><<<dim3(8, 64), 512, 131072, stream>>>(zm, w1b, b1, h1, nullptr, nullptr, nullptr);
    gemm256<0, 2048, 2048><<<dim3(8, 64), 512, 131072, stream>>>(h1, w2b, b2, h2, nullptr, nullptr, nullptr);
    gemm256<2, 2048, 1024><<<dim3(4, 64), 512, 131072, stream>>>(h2, w3i, b3i, nullptr, zout, z, ldout);
}

// Round 9
// 357.532 us; speedup vs baseline: 3.8545x; 1.0213x over previous
//
#include <hip/hip_runtime.h>
#include <hip/hip_bf16.h>
#include <cstdint>

typedef __bf16 bf16x8 __attribute__((ext_vector_type(8)));
typedef float  f32x4  __attribute__((ext_vector_type(4)));

struct alignas(4) us2 { unsigned short x, y; };
struct alignas(8) us4 { unsigned short x, y, z, w; };

__device__ __forceinline__ unsigned short f2bf(float f) {
    union { float f; unsigned u; } a; a.f = f;
    unsigned r = a.u + 0x7fffu + ((a.u >> 16) & 1u);   // round-to-nearest-even
    return (unsigned short)(r >> 16);
}

__device__ __forceinline__ void gl_lds16(const void* g, void* s) {
    __builtin_amdgcn_global_load_lds(
        (const __attribute__((address_space(1))) void*)g,
        (__attribute__((address_space(3))) void*)s, 16, 0, 0);
}

#define SCHEDB()  __builtin_amdgcn_sched_barrier(0)
#define SBAR()    do { SCHEDB(); __builtin_amdgcn_s_barrier(); SCHEDB(); } while (0)
#define WAITLG(N) do { asm volatile("s_waitcnt lgkmcnt(" #N ")" ::: "memory"); SCHEDB(); } while (0)
#define WAITVM(N) do { asm volatile("s_waitcnt vmcnt(" #N ")" ::: "memory"); SCHEDB(); } while (0)

// C = A(MxK) @ W(NxK)^T, bf16 in, fp32 acc. 256x256 tile, 8 waves (2Mx4N).
// m201 "2dbuf x 2half" geometry: ring of 4 K-32 half-slots (A 16KB + B 16KB each,
// 128KB total). Compute half h (slot h&3), stage half h+3 (slot (h+3)&3 = the slot
// read in half h-1, safe after the top-of-h barrier). Top-of-half cert:
// COUNTED WAITVM(8) (2 halves stay in flight; never drains in steady state) ->
// prefetch distance 3 halves (~1300cyc) > HBM latency. Per half: 2 phases
// {reads -> stage -> BARRIER -> lgkmcnt(0) -> setprio -> 16 MFMA}: barrier absorbs
// ds_read latency. Swizzle (bank-balanced, 0-conflict class): stored chunk pos
// p = src_kchunk ^ (row&3) in 64B rows; read xo = ((lane>>4)^(ln15&3))*16.
// EPI 0: outb = bf16(gelu_exact(acc+bias)) ; EPI 1: outf = acc+bias ;
// EPI 2: fused coupling (W interleaved s/t): even col -> s, odd -> t.
// Epilogue loops mi,r,nf-inner: one row's 4 col-segments stored back-to-back
// (write-combine; R7 measured 2.35x write amplification with nf-outer order).
template<int EPI, int K, int N>
__global__ __launch_bounds__(512, 2)
void gemm256(const unsigned short* __restrict__ A,
             const unsigned short* __restrict__ W,
             const float* __restrict__ bias,
             unsigned short* __restrict__ outb,
             float* __restrict__ outf,
             const float* __restrict__ zin,
             float* __restrict__ ldout)
{
    extern __shared__ char smem[];
    constexpr int NH = K / 32;           // number of K-32 halves
    constexpr int GX = N / 256;

    const int tid  = threadIdx.x;
    const int lane = tid & 63;
    const int wv   = tid >> 6;           // 0..7
    const int wr   = wv >> 2, wc = wv & 3;

    // T1: bijective XCD swizzle (nwg divisible by 8 for all our shapes)
    const int bid = blockIdx.y * GX + blockIdx.x;
    const int nwg = GX * (int)gridDim.y;
    const int swz = (bid & 7) * (nwg >> 3) + (bid >> 3);
    const size_t row0 = (size_t)(swz / GX) * 256;
    const size_t col0 = (size_t)(swz % GX) * 256;

    // LDS: A ring = 4 x 16KB at +0 ; B ring = 4 x 16KB at +65536.
    // Half-slot layout: 256 rows x 64B (32 bf16). Chunk c (16B): row c>>2,
    // pos c&3, holds src k-chunk (c&3)^(row&3).
    // Staging: thread tid writes chunks {tid, 512+tid} per matrix:
    // row = (tid>>2) + j*128, pos = tid&3 -> src k-chunk = (tid&3)^((tid>>2)&3).
    const int cse = (((tid & 3) ^ ((tid >> 2) & 3)) << 3);  // src elem offset
    const unsigned short* ag = A + (row0 + (tid >> 2)) * (size_t)K + cse;
    const unsigned short* bg = W + (col0 + (tid >> 2)) * (size_t)K + cse;

    auto stage = [&](int hh) {           // 4 x gl_lds (A j0,j1 ; B j0,j1)
        char* dA = smem + (hh & 3) * 16384 + tid * 16;
        char* dB = dA + 65536;
        const unsigned short* a = ag + (size_t)hh * 32;
        const unsigned short* b = bg + (size_t)hh * 32;
        gl_lds16(a,                     dA);
        gl_lds16(a + (size_t)128 * K,   dA + 8192);
        gl_lds16(b,                     dB);
        gl_lds16(b + (size_t)128 * K,   dB + 8192);
    };

    // fragment reads: byte = row*64 + ((lane>>4)^(row&3))*16 ; row&3 == ln15&3
    const int ln15 = lane & 15;
    const int xo   = (((lane >> 4) ^ (ln15 & 3)) << 4);
    const int arow = wr * 128 + ln15;                       // + mi*16 (mi 0..7)
    const int brow = wc * 64 + ln15;                        // + nf*16 (nf 0..3)

#define LD(base, row) (*(const bf16x8*)((base) + (size_t)(row) * 64 + xo))

    f32x4 acc[8][4] = {};

    // prologue: stage halves 0,1,2 (12 loads in flight)
    stage(0); stage(1); stage(2);

    for (int h = 0; h < NH; ++h) {
        const char* cA = smem + (h & 3) * 16384;
        const char* cB = cA + 65536;

        // top-of-half cert: counted (halves h+1,h+2 stay in flight)
        if (h < NH - 2)       WAITVM(8);
        else if (h == NH - 2) WAITVM(4);
        else                  WAITVM(0);
        SBAR();

        bf16x8 aF[8], bF[4];
        // ===== phase 0: read aF[0..3]+bF[0..3]; stage h+3; 16 MFMA =====
#pragma unroll
        for (int mf = 0; mf < 4; ++mf) aF[mf] = LD(cA, arow + mf * 16);
#pragma unroll
        for (int nf = 0; nf < 4; ++nf) bF[nf] = LD(cB, brow + nf * 16);
        if (h + 3 < NH) stage(h + 3);
        SBAR();
        WAITLG(0);
        __builtin_amdgcn_s_setprio(1);
#pragma unroll
        for (int mf = 0; mf < 4; ++mf)
#pragma unroll
            for (int nf = 0; nf < 4; ++nf)
                acc[mf][nf] = __builtin_amdgcn_mfma_f32_16x16x32_bf16(
                    aF[mf], bF[nf], acc[mf][nf], 0, 0, 0);
        __builtin_amdgcn_s_setprio(0);
        SBAR();

        // ===== phase 1: read aF[4..7]; 16 MFMA =====
#pragma unroll
        for (int mf = 4; mf < 8; ++mf) aF[mf] = LD(cA, arow + mf * 16);
        SBAR();
        WAITLG(0);
        __builtin_amdgcn_s_setprio(1);
#pragma unroll
        for (int mf = 4; mf < 8; ++mf)
#pragma unroll
            for (int nf = 0; nf < 4; ++nf)
                acc[mf][nf] = __builtin_amdgcn_mfma_f32_16x16x32_bf16(
                    aF[mf], bF[nf], acc[mf][nf], 0, 0, 0);
        __builtin_amdgcn_s_setprio(0);
    }
#undef LD

    // epilogue: D layout col = lane&15, row = (lane>>4)*4 + reg
    const int lq = lane >> 4;
    float bv[4];
#pragma unroll
    for (int nf = 0; nf < 4; ++nf) bv[nf] = bias[col0 + wc * 64 + nf * 16 + ln15];

    if (EPI == 2) {
        const bool odd = (ln15 & 1);
#pragma unroll
        for (int mi = 0; mi < 8; ++mi) {
#pragma unroll
            for (int r = 0; r < 4; ++r) {
                const size_t row = row0 + wr * 128 + mi * 16 + lq * 4 + r;
#pragma unroll
                for (int nf = 0; nf < 4; ++nf) {
                    const size_t col = col0 + wc * 64 + nf * 16 + ln15;
                    float v = acc[mi][nf][r] + bv[nf];       // even lane: s, odd: t
                    float partner = __shfl_xor(v, 1, 64);
                    float zv = zin[row * N + col];
                    float res = odd ? (zv * __expf(partner) + v) : zv;
                    outf[row * N + col] = res;
                }
            }
        }
        // log_det partials: sum of s (even-lane v) per row
#pragma unroll
        for (int mi = 0; mi < 8; ++mi) {
#pragma unroll
            for (int r = 0; r < 4; ++r) {
                float sv = 0.f;
#pragma unroll
                for (int nf = 0; nf < 4; ++nf) sv += acc[mi][nf][r] + bv[nf];
                sv = odd ? 0.f : sv;
#pragma unroll
                for (int off = 1; off < 16; off <<= 1) sv += __shfl_xor(sv, off, 64);
                if (ln15 == 0) {
                    const size_t row = row0 + wr * 128 + mi * 16 + lq * 4 + r;
                    atomicAdd(&ldout[row], sv);
                }
            }
        }
    } else {
#pragma unroll
        for (int mi = 0; mi < 8; ++mi) {
#pragma unroll
            for (int r = 0; r < 4; ++r) {
                const size_t row = row0 + wr * 128 + mi * 16 + lq * 4 + r;
#pragma unroll
                for (int nf = 0; nf < 4; ++nf) {
                    const size_t col = col0 + wc * 64 + nf * 16 + ln15;
                    float v = acc[mi][nf][r] + bv[nf];
                    if (EPI == 0) {
                        float g = 0.5f * v * (1.0f + erff(v * 0.70710678118654752f));
                        outb[row * N + col] = f2bf(g);
                    } else {
                        outf[row * N + col] = v;
                    }
                }
            }
        }
    }
}

__global__ void cvt_bf16(const float* __restrict__ in, unsigned short* __restrict__ out, int n4) {
    const int stride = gridDim.x * blockDim.x;
    for (int i = blockIdx.x * blockDim.x + threadIdx.x; i < n4; i += stride) {
        float4 v = ((const float4*)in)[i];
        us4 o{ f2bf(v.x), f2bf(v.y), f2bf(v.z), f2bf(v.w) };
        ((us4*)out)[i] = o;
    }
}

// W3 interleaved convert: out row c (0..1023) = W3 row (c&1 ? 512+(c>>1) : c>>1)
__global__ void cvt_w3i(const float* __restrict__ in, unsigned short* __restrict__ out, int n4) {
    const int stride = gridDim.x * blockDim.x;
    for (int i = blockIdx.x * blockDim.x + threadIdx.x; i < n4; i += stride) {
        int row = i >> 9;           // 512 float4 per 2048-col row
        int c4  = i & 511;
        int srcrow = (row & 1) ? 512 + (row >> 1) : (row >> 1);
        float4 v = ((const float4*)in)[srcrow * 512 + c4];
        us4 o{ f2bf(v.x), f2bf(v.y), f2bf(v.z), f2bf(v.w) };
        ((us4*)out)[i] = o;
    }
}

// zm[row][i] = bf16(z[row][2i])
__global__ void pack_even(const float* __restrict__ z, unsigned short* __restrict__ zm, int n4) {
    const int stride = gridDim.x * blockDim.x;
    for (int i = blockIdx.x * blockDim.x + threadIdx.x; i < n4; i += stride) {
        float4 v = ((const float4*)z)[i];
        us2 o{ f2bf(v.x), f2bf(v.z) };
        ((us2*)zm)[i] = o;
    }
}

// b3 interleave + ldout init
__global__ void prep3(const float* __restrict__ b3, float* __restrict__ b3i,
                      const float* __restrict__ ld, float* __restrict__ ldout, int nrow) {
    const int stride = gridDim.x * blockDim.x;
    int i = blockIdx.x * blockDim.x + threadIdx.x;
    if (i < 1024) b3i[i] = b3[(i & 1) ? 512 + (i >> 1) : (i >> 1)];
    for (int r = i; r < nrow; r += stride) ldout[r] = ld[r];
}

extern "C" void kernel_launch(void* const* d_in, const int* in_sizes, int n_in,
                              void* d_out, int out_size, void* d_ws, size_t ws_size,
                              hipStream_t stream)
{
    const float* z  = (const float*)d_in[0];
    const float* ld = (const float*)d_in[1];
    const float* W1 = (const float*)d_in[2];
    const float* b1 = (const float*)d_in[3];
    const float* W2 = (const float*)d_in[4];
    const float* b2 = (const float*)d_in[5];
    const float* W3 = (const float*)d_in[6];
    const float* b3 = (const float*)d_in[7];

    float* out   = (float*)d_out;
    float* zout  = out;
    float* ldout = out + (size_t)16384 * 1024;

    char* w = (char*)d_ws;
    unsigned short* zm  = (unsigned short*)w; w += (size_t)16384 * 512 * 2;
    unsigned short* w1b = (unsigned short*)w; w += (size_t)2048 * 512 * 2;
    unsigned short* w2b = (unsigned short*)w; w += (size_t)2048 * 2048 * 2;
    unsigned short* w3i = (unsigned short*)w; w += (size_t)1024 * 2048 * 2;
    unsigned short* h1  = (unsigned short*)w; w += (size_t)16384 * 2048 * 2;
    unsigned short* h2  = (unsigned short*)w; w += (size_t)16384 * 2048 * 2;
    float*          b3i = (float*)w;          w += 1024 * 4;

    (void)hipFuncSetAttribute((const void*)&gemm256<0, 512,  2048>,
                              hipFuncAttributeMaxDynamicSharedMemorySize, 131072);
    (void)hipFuncSetAttribute((const void*)&gemm256<0, 2048, 2048>,
                              hipFuncAttributeMaxDynamicSharedMemorySize, 131072);
    (void)hipFuncSetAttribute((const void*)&gemm256<2, 2048, 1024>,
                              hipFuncAttributeMaxDynamicSharedMemorySize, 131072);

    cvt_bf16 <<<512,  256, 0, stream>>>(W1, w1b, 2048 * 512 / 4);
    cvt_bf16 <<<2048, 256, 0, stream>>>(W2, w2b, 2048 * 2048 / 4);
    cvt_w3i  <<<1024, 256, 0, stream>>>(W3, w3i, 1024 * 2048 / 4);
    pack_even<<<2048, 256, 0, stream>>>(z, zm, 16384 * 1024 / 4);
    prep3    <<<64,   256, 0, stream>>>(b3, b3i, ld, ldout, 16384);

    gemm256<0, 512,  2048><<<dim3(8, 64), 512, 131072, stream>>>(zm, w1b, b1, h1, nullptr, nullptr, nullptr);
    gemm256<0, 2048, 2048><<<dim3(8, 64), 512, 131072, stream>>>(h1, w2b, b2, h2, nullptr, nullptr, nullptr);
    gemm256<2, 2048, 1024><<<dim3(4, 64), 512, 131072, stream>>>(h2, w3i, b3i, nullptr, zout, z, ldout);
}

// Round 10
// 338.431 us; speedup vs baseline: 4.0720x; 1.0564x over previous
//
#include <hip/hip_runtime.h>
#include <hip/hip_bf16.h>
#include <cstdint>

typedef __bf16 bf16x8 __attribute__((ext_vector_type(8)));
typedef float  f32x4  __attribute__((ext_vector_type(4)));

struct alignas(4) us2 { unsigned short x, y; };
struct alignas(8) us4 { unsigned short x, y, z, w; };

__device__ __forceinline__ unsigned short f2bf(float f) {
    union { float f; unsigned u; } a; a.f = f;
    unsigned r = a.u + 0x7fffu + ((a.u >> 16) & 1u);   // round-to-nearest-even
    return (unsigned short)(r >> 16);
}

__device__ __forceinline__ void gl_lds16(const void* g, void* s) {
    __builtin_amdgcn_global_load_lds(
        (const __attribute__((address_space(1))) void*)g,
        (__attribute__((address_space(3))) void*)s, 16, 0, 0);
}

#define SCHEDB()  __builtin_amdgcn_sched_barrier(0)
#define SBAR()    do { SCHEDB(); __builtin_amdgcn_s_barrier(); SCHEDB(); } while (0)
#define WAITLG(N) do { asm volatile("s_waitcnt lgkmcnt(" #N ")" ::: "memory"); SCHEDB(); } while (0)
#define WAITVM(N) do { asm volatile("s_waitcnt vmcnt(" #N ")" ::: "memory"); SCHEDB(); } while (0)

// C = A(MxK) @ W(NxK)^T, bf16 in, fp32 acc. 256x256 tile, 8 waves (2Mx4N).
// Ring of 4 K-32 half-slots (A 16KB + B 16KB each, 128KB total). Compute half h
// (slot h&3), stage half h+3. Top-of-half cert: COUNTED WAITVM(8) (2 halves stay
// in flight; prefetch distance 3 halves > HBM latency). Per half: 2 phases
// {reads -> stage -> BARRIER -> lgkmcnt(0) -> setprio -> 16 MFMA}: barrier
// absorbs ds_read latency.
// Swizzle: R3-proven row-bits[2:1] XOR (0 conflicts measured): stored chunk pos
// p = src_kchunk ^ ((row>>1)&3); read xo = ((lane>>4)^((ln15>>1)&3))*16.
// (R9 used row bits [1:0] -> 1.26e7 conflicts, the exact R2 bug. Reverted.)
// EPI 0: outb = bf16(gelu_exact(acc+bias)) ; EPI 1: outf = acc+bias ;
// EPI 2: fused coupling (W interleaved s/t): even col -> s, odd -> t.
// Epilogue mi,r,nf-inner (write-combine; measured WRITE 158->65.5 MB = ideal).
template<int EPI, int K, int N>
__global__ __launch_bounds__(512, 2)
void gemm256(const unsigned short* __restrict__ A,
             const unsigned short* __restrict__ W,
             const float* __restrict__ bias,
             unsigned short* __restrict__ outb,
             float* __restrict__ outf,
             const float* __restrict__ zin,
             float* __restrict__ ldout)
{
    extern __shared__ char smem[];
    constexpr int NH = K / 32;           // number of K-32 halves
    constexpr int GX = N / 256;

    const int tid  = threadIdx.x;
    const int lane = tid & 63;
    const int wv   = tid >> 6;           // 0..7
    const int wr   = wv >> 2, wc = wv & 3;

    // T1: bijective XCD swizzle (nwg divisible by 8 for all our shapes)
    const int bid = blockIdx.y * GX + blockIdx.x;
    const int nwg = GX * (int)gridDim.y;
    const int swz = (bid & 7) * (nwg >> 3) + (bid >> 3);
    const size_t row0 = (size_t)(swz / GX) * 256;
    const size_t col0 = (size_t)(swz % GX) * 256;

    // LDS: A ring = 4 x 16KB at +0 ; B ring = 4 x 16KB at +65536.
    // Half-slot: 256 rows x 64B. Chunk c (16B): row c>>2, pos c&3, holds
    // src k-chunk (c&3) ^ ((row>>1)&3)   [R3 swizzle, 0-conflict]
    // Staging: thread tid -> row tid>>2 (+128 for j=1), pos tid&3:
    // src k-chunk = (tid&3) ^ ((tid>>3)&3)  (row+128 preserves bits[2:1] mod 4).
    const int cse = (((tid & 3) ^ ((tid >> 3) & 3)) << 3);  // src elem offset
    const unsigned short* ag = A + (row0 + (tid >> 2)) * (size_t)K + cse;
    const unsigned short* bg = W + (col0 + (tid >> 2)) * (size_t)K + cse;

    auto stage = [&](int hh) {           // 4 x gl_lds (A j0,j1 ; B j0,j1)
        char* dA = smem + (hh & 3) * 16384 + tid * 16;
        char* dB = dA + 65536;
        const unsigned short* a = ag + (size_t)hh * 32;
        const unsigned short* b = bg + (size_t)hh * 32;
        gl_lds16(a,                     dA);
        gl_lds16(a + (size_t)128 * K,   dA + 8192);
        gl_lds16(b,                     dB);
        gl_lds16(b + (size_t)128 * K,   dB + 8192);
    };

    // fragment reads: byte = row*64 + ((lane>>4) ^ ((row>>1)&3))*16 ;
    // (row>>1)&3 == (ln15>>1)&3 (row offsets are multiples of 16)
    const int ln15 = lane & 15;
    const int xo   = (((lane >> 4) ^ ((ln15 >> 1) & 3)) << 4);
    const int arow = wr * 128 + ln15;                       // + mi*16 (mi 0..7)
    const int brow = wc * 64 + ln15;                        // + nf*16 (nf 0..3)

#define LD(base, row) (*(const bf16x8*)((base) + (size_t)(row) * 64 + xo))

    f32x4 acc[8][4] = {};

    // prologue: stage halves 0,1,2 (12 loads in flight)
    stage(0); stage(1); stage(2);

    for (int h = 0; h < NH; ++h) {
        const char* cA = smem + (h & 3) * 16384;
        const char* cB = cA + 65536;

        // top-of-half cert: counted (halves h+1,h+2 stay in flight)
        if (h < NH - 2)       WAITVM(8);
        else if (h == NH - 2) WAITVM(4);
        else                  WAITVM(0);
        SBAR();

        bf16x8 aF[8], bF[4];
        // ===== phase 0: read aF[0..3]+bF[0..3]; stage h+3; 16 MFMA =====
#pragma unroll
        for (int mf = 0; mf < 4; ++mf) aF[mf] = LD(cA, arow + mf * 16);
#pragma unroll
        for (int nf = 0; nf < 4; ++nf) bF[nf] = LD(cB, brow + nf * 16);
        if (h + 3 < NH) stage(h + 3);
        SBAR();
        WAITLG(0);
        __builtin_amdgcn_s_setprio(1);
#pragma unroll
        for (int mf = 0; mf < 4; ++mf)
#pragma unroll
            for (int nf = 0; nf < 4; ++nf)
                acc[mf][nf] = __builtin_amdgcn_mfma_f32_16x16x32_bf16(
                    aF[mf], bF[nf], acc[mf][nf], 0, 0, 0);
        __builtin_amdgcn_s_setprio(0);
        SBAR();

        // ===== phase 1: read aF[4..7]; 16 MFMA =====
#pragma unroll
        for (int mf = 4; mf < 8; ++mf) aF[mf] = LD(cA, arow + mf * 16);
        SBAR();
        WAITLG(0);
        __builtin_amdgcn_s_setprio(1);
#pragma unroll
        for (int mf = 4; mf < 8; ++mf)
#pragma unroll
            for (int nf = 0; nf < 4; ++nf)
                acc[mf][nf] = __builtin_amdgcn_mfma_f32_16x16x32_bf16(
                    aF[mf], bF[nf], acc[mf][nf], 0, 0, 0);
        __builtin_amdgcn_s_setprio(0);
    }
#undef LD

    // epilogue: D layout col = lane&15, row = (lane>>4)*4 + reg
    const int lq = lane >> 4;
    float bv[4];
#pragma unroll
    for (int nf = 0; nf < 4; ++nf) bv[nf] = bias[col0 + wc * 64 + nf * 16 + ln15];

    if (EPI == 2) {
        const bool odd = (ln15 & 1);
#pragma unroll
        for (int mi = 0; mi < 8; ++mi) {
#pragma unroll
            for (int r = 0; r < 4; ++r) {
                const size_t row = row0 + wr * 128 + mi * 16 + lq * 4 + r;
#pragma unroll
                for (int nf = 0; nf < 4; ++nf) {
                    const size_t col = col0 + wc * 64 + nf * 16 + ln15;
                    float v = acc[mi][nf][r] + bv[nf];       // even lane: s, odd: t
                    float partner = __shfl_xor(v, 1, 64);
                    float zv = zin[row * N + col];
                    float res = odd ? (zv * __expf(partner) + v) : zv;
                    outf[row * N + col] = res;
                }
            }
        }
        // log_det partials: sum of s (even-lane v) per row
#pragma unroll
        for (int mi = 0; mi < 8; ++mi) {
#pragma unroll
            for (int r = 0; r < 4; ++r) {
                float sv = 0.f;
#pragma unroll
                for (int nf = 0; nf < 4; ++nf) sv += acc[mi][nf][r] + bv[nf];
                sv = odd ? 0.f : sv;
#pragma unroll
                for (int off = 1; off < 16; off <<= 1) sv += __shfl_xor(sv, off, 64);
                if (ln15 == 0) {
                    const size_t row = row0 + wr * 128 + mi * 16 + lq * 4 + r;
                    atomicAdd(&ldout[row], sv);
                }
            }
        }
    } else {
#pragma unroll
        for (int mi = 0; mi < 8; ++mi) {
#pragma unroll
            for (int r = 0; r < 4; ++r) {
                const size_t row = row0 + wr * 128 + mi * 16 + lq * 4 + r;
#pragma unroll
                for (int nf = 0; nf < 4; ++nf) {
                    const size_t col = col0 + wc * 64 + nf * 16 + ln15;
                    float v = acc[mi][nf][r] + bv[nf];
                    if (EPI == 0) {
                        float g = 0.5f * v * (1.0f + erff(v * 0.70710678118654752f));
                        outb[row * N + col] = f2bf(g);
                    } else {
                        outf[row * N + col] = v;
                    }
                }
            }
        }
    }
}

__global__ void cvt_bf16(const float* __restrict__ in, unsigned short* __restrict__ out, int n4) {
    const int stride = gridDim.x * blockDim.x;
    for (int i = blockIdx.x * blockDim.x + threadIdx.x; i < n4; i += stride) {
        float4 v = ((const float4*)in)[i];
        us4 o{ f2bf(v.x), f2bf(v.y), f2bf(v.z), f2bf(v.w) };
        ((us4*)out)[i] = o;
    }
}

// W3 interleaved convert: out row c (0..1023) = W3 row (c&1 ? 512+(c>>1) : c>>1)
__global__ void cvt_w3i(const float* __restrict__ in, unsigned short* __restrict__ out, int n4) {
    const int stride = gridDim.x * blockDim.x;
    for (int i = blockIdx.x * blockDim.x + threadIdx.x; i < n4; i += stride) {
        int row = i >> 9;           // 512 float4 per 2048-col row
        int c4  = i & 511;
        int srcrow = (row & 1) ? 512 + (row >> 1) : (row >> 1);
        float4 v = ((const float4*)in)[srcrow * 512 + c4];
        us4 o{ f2bf(v.x), f2bf(v.y), f2bf(v.z), f2bf(v.w) };
        ((us4*)out)[i] = o;
    }
}

// zm[row][i] = bf16(z[row][2i])
__global__ void pack_even(const float* __restrict__ z, unsigned short* __restrict__ zm, int n4) {
    const int stride = gridDim.x * blockDim.x;
    for (int i = blockIdx.x * blockDim.x + threadIdx.x; i < n4; i += stride) {
        float4 v = ((const float4*)z)[i];
        us2 o{ f2bf(v.x), f2bf(v.z) };
        ((us2*)zm)[i] = o;
    }
}

// b3 interleave + ldout init
__global__ void prep3(const float* __restrict__ b3, float* __restrict__ b3i,
                      const float* __restrict__ ld, float* __restrict__ ldout, int nrow) {
    const int stride = gridDim.x * blockDim.x;
    int i = blockIdx.x * blockDim.x + threadIdx.x;
    if (i < 1024) b3i[i] = b3[(i & 1) ? 512 + (i >> 1) : (i >> 1)];
    for (int r = i; r < nrow; r += stride) ldout[r] = ld[r];
}

extern "C" void kernel_launch(void* const* d_in, const int* in_sizes, int n_in,
                              void* d_out, int out_size, void* d_ws, size_t ws_size,
                              hipStream_t stream)
{
    const float* z  = (const float*)d_in[0];
    const float* ld = (const float*)d_in[1];
    const float* W1 = (const float*)d_in[2];
    const float* b1 = (const float*)d_in[3];
    const float* W2 = (const float*)d_in[4];
    const float* b2 = (const float*)d_in[5];
    const float* W3 = (const float*)d_in[6];
    const float* b3 = (const float*)d_in[7];

    float* out   = (float*)d_out;
    float* zout  = out;
    float* ldout = out + (size_t)16384 * 1024;

    char* w = (char*)d_ws;
    unsigned short* zm  = (unsigned short*)w; w += (size_t)16384 * 512 * 2;
    unsigned short* w1b = (unsigned short*)w; w += (size_t)2048 * 512 * 2;
    unsigned short* w2b = (unsigned short*)w; w += (size_t)2048 * 2048 * 2;
    unsigned short* w3i = (unsigned short*)w; w += (size_t)1024 * 2048 * 2;
    unsigned short* h1  = (unsigned short*)w; w += (size_t)16384 * 2048 * 2;
    unsigned short* h2  = (unsigned short*)w; w += (size_t)16384 * 2048 * 2;
    float*          b3i = (float*)w;          w += 1024 * 4;

    (void)hipFuncSetAttribute((const void*)&gemm256<0, 512,  2048>,
                              hipFuncAttributeMaxDynamicSharedMemorySize, 131072);
    (void)hipFuncSetAttribute((const void*)&gemm256<0, 2048, 2048>,
                              hipFuncAttributeMaxDynamicSharedMemorySize, 131072);
    (void)hipFuncSetAttribute((const void*)&gemm256<2, 2048, 1024>,
                              hipFuncAttributeMaxDynamicSharedMemorySize, 131072);

    cvt_bf16 <<<512,  256, 0, stream>>>(W1, w1b, 2048 * 512 / 4);
    cvt_bf16 <<<2048, 256, 0, stream>>>(W2, w2b, 2048 * 2048 / 4);
    cvt_w3i  <<<1024, 256, 0, stream>>>(W3, w3i, 1024 * 2048 / 4);
    pack_even<<<2048, 256, 0, stream>>>(z, zm, 16384 * 1024 / 4);
    prep3    <<<64,   256, 0, stream>>>(b3, b3i, ld, ldout, 16384);

    gemm256<0, 512,  2048><<<dim3(8, 64), 512, 131072, stream>>>(zm, w1b, b1, h1, nullptr, nullptr, nullptr);
    gemm256<0, 2048, 2048><<<dim3(8, 64), 512, 131072, stream>>>(h1, w2b, b2, h2, nullptr, nullptr, nullptr);
    gemm256<2, 2048, 1024><<<dim3(4, 64), 512, 131072, stream>>>(h2, w3i, b3i, nullptr, zout, z, ldout);
}

// Round 11
// 332.227 us; speedup vs baseline: 4.1481x; 1.0187x over previous
//
#include <hip/hip_runtime.h>
#include <hip/hip_bf16.h>
#include <cstdint>

typedef __bf16 bf16x8 __attribute__((ext_vector_type(8)));
typedef float  f32x4  __attribute__((ext_vector_type(4)));

struct alignas(4) us2 { unsigned short x, y; };
struct alignas(8) us4 { unsigned short x, y, z, w; };

__device__ __forceinline__ unsigned short f2bf(float f) {
    union { float f; unsigned u; } a; a.f = f;
    unsigned r = a.u + 0x7fffu + ((a.u >> 16) & 1u);   // round-to-nearest-even
    return (unsigned short)(r >> 16);
}

__device__ __forceinline__ void gl_lds16(const void* g, void* s) {
    __builtin_amdgcn_global_load_lds(
        (const __attribute__((address_space(1))) void*)g,
        (__attribute__((address_space(3))) void*)s, 16, 0, 0);
}

#define SCHEDB()  __builtin_amdgcn_sched_barrier(0)
#define SBAR()    do { SCHEDB(); __builtin_amdgcn_s_barrier(); SCHEDB(); } while (0)
#define WAITLG(N) do { asm volatile("s_waitcnt lgkmcnt(" #N ")" ::: "memory"); SCHEDB(); } while (0)
#define WAITVM(N) do { asm volatile("s_waitcnt vmcnt(" #N ")" ::: "memory"); SCHEDB(); } while (0)

// C = A(MxK) @ W(NxK)^T, bf16 in, fp32 acc. 256x256 tile, 8 waves (2Mx4N).
// Ring of 4 K-32 half-slots (A 16KB + B 16KB, 128KB). Stage h+3 during h.
// FREE-RUN half (R11): ONE barrier per half (top: counted WAITVM(8) certifies own
// DMA writes, then SBAR -> all waves' writes certified & slot-reuse safe).
// No intra-half barriers: reads-after-reads need none; waves drift so LDS service
// overlaps other waves' MFMA clusters. Own-read certification via counted lgkm:
// issue all 12 reads -> WAITLG(4) -> 16 MFMA -> WAITLG(0) -> 16 MFMA.
// Swizzle: R3-proven row-bits[2:1] XOR (0 conflicts measured).
// EPI 0: outb = bf16(gelu_exact(acc+bias)) ; EPI 1: outf = acc+bias ;
// EPI 2: fused coupling, W3 interleaved by 16-col blocks (s-block | t-block):
//   lane owns (s,t) pair in nf=2p / 2p+1 -> no shuffles, float2-coalesced I/O.
template<int EPI, int K, int N>
__global__ __launch_bounds__(512, 2)
void gemm256(const unsigned short* __restrict__ A,
             const unsigned short* __restrict__ W,
             const float* __restrict__ bias,
             unsigned short* __restrict__ outb,
             float* __restrict__ outf,
             const float* __restrict__ zin,
             float* __restrict__ ldout)
{
    extern __shared__ char smem[];
    constexpr int NH = K / 32;           // number of K-32 halves
    constexpr int GX = N / 256;

    const int tid  = threadIdx.x;
    const int lane = tid & 63;
    const int wv   = tid >> 6;           // 0..7
    const int wr   = wv >> 2, wc = wv & 3;

    // T1: bijective XCD swizzle (nwg divisible by 8 for all our shapes)
    const int bid = blockIdx.y * GX + blockIdx.x;
    const int nwg = GX * (int)gridDim.y;
    const int swz = (bid & 7) * (nwg >> 3) + (bid >> 3);
    const size_t row0 = (size_t)(swz / GX) * 256;
    const size_t col0 = (size_t)(swz % GX) * 256;

    // LDS: A ring = 4 x 16KB at +0 ; B ring = 4 x 16KB at +65536.
    // Half-slot: 256 rows x 64B. Chunk c (16B): row c>>2, pos c&3, holds
    // src k-chunk (c&3) ^ ((row>>1)&3)   [R3 swizzle, 0-conflict]
    const int cse = (((tid & 3) ^ ((tid >> 3) & 3)) << 3);  // src elem offset
    const unsigned short* ag = A + (row0 + (tid >> 2)) * (size_t)K + cse;
    const unsigned short* bg = W + (col0 + (tid >> 2)) * (size_t)K + cse;

    auto stage = [&](int hh) {           // 4 x gl_lds (A j0,j1 ; B j0,j1)
        char* dA = smem + (hh & 3) * 16384 + tid * 16;
        char* dB = dA + 65536;
        const unsigned short* a = ag + (size_t)hh * 32;
        const unsigned short* b = bg + (size_t)hh * 32;
        gl_lds16(a,                     dA);
        gl_lds16(a + (size_t)128 * K,   dA + 8192);
        gl_lds16(b,                     dB);
        gl_lds16(b + (size_t)128 * K,   dB + 8192);
    };

    // fragment reads: byte = row*64 + ((lane>>4) ^ ((row>>1)&3))*16
    const int ln15 = lane & 15;
    const int xo   = (((lane >> 4) ^ ((ln15 >> 1) & 3)) << 4);
    const int arow = wr * 128 + ln15;                       // + mi*16 (mi 0..7)
    const int brow = wc * 64 + ln15;                        // + nf*16 (nf 0..3)

#define LD(base, row) (*(const bf16x8*)((base) + (size_t)(row) * 64 + xo))

    f32x4 acc[8][4] = {};

    // prologue: stage halves 0,1,2 (12 loads in flight)
    stage(0); stage(1); stage(2);

    for (int h = 0; h < NH; ++h) {
        const char* cA = smem + (h & 3) * 16384;
        const char* cB = cA + 65536;

        // top-of-half: counted cert (own stage(h) writes landed), then barrier
        if (h < NH - 2)       WAITVM(8);
        else if (h == NH - 2) WAITVM(4);
        else                  WAITVM(0);
        SBAR();

        bf16x8 aF[8], bF[4];
        // issue ALL reads up-front (order pinned: group0 = aF0-3+bF0-3)
#pragma unroll
        for (int mf = 0; mf < 4; ++mf) aF[mf] = LD(cA, arow + mf * 16);
#pragma unroll
        for (int nf = 0; nf < 4; ++nf) bF[nf] = LD(cB, brow + nf * 16);
        SCHEDB();
#pragma unroll
        for (int mf = 4; mf < 8; ++mf) aF[mf] = LD(cA, arow + mf * 16);
        SCHEDB();
        if (h + 3 < NH) stage(h + 3);

        WAITLG(4);                       // aF0-3 + bF0-3 certified; aF4-7 float
        __builtin_amdgcn_s_setprio(1);
#pragma unroll
        for (int mf = 0; mf < 4; ++mf)
#pragma unroll
            for (int nf = 0; nf < 4; ++nf)
                acc[mf][nf] = __builtin_amdgcn_mfma_f32_16x16x32_bf16(
                    aF[mf], bF[nf], acc[mf][nf], 0, 0, 0);
        __builtin_amdgcn_s_setprio(0);

        WAITLG(0);                       // aF4-7 certified
        __builtin_amdgcn_s_setprio(1);
#pragma unroll
        for (int mf = 4; mf < 8; ++mf)
#pragma unroll
            for (int nf = 0; nf < 4; ++nf)
                acc[mf][nf] = __builtin_amdgcn_mfma_f32_16x16x32_bf16(
                    aF[mf], bF[nf], acc[mf][nf], 0, 0, 0);
        __builtin_amdgcn_s_setprio(0);
    }
#undef LD

    // epilogue: D layout col = lane&15, row = (lane>>4)*4 + reg
    const int lq = lane >> 4;
    float bv[4];
#pragma unroll
    for (int nf = 0; nf < 4; ++nf) bv[nf] = bias[col0 + wc * 64 + nf * 16 + ln15];

    if (EPI == 2) {
        // W interleaved by 16-col blocks: col c: q=c>>5,u=c&31; u<16 -> s_{16q+u},
        // u>=16 -> t_{16q+u-16}. Lane (nf=2p even) holds s, (nf=2p+1) holds t for
        // the SAME j = 16*q_g + ln15, q_g = col0/32 + wc*2 + p.
        const float2* zin2 = (const float2*)zin;
        float2*       out2 = (float2*)outf;
#pragma unroll
        for (int mi = 0; mi < 8; ++mi) {
#pragma unroll
            for (int r = 0; r < 4; ++r) {
                const size_t row = row0 + wr * 128 + mi * 16 + lq * 4 + r;
                float sv = 0.f;
#pragma unroll
                for (int p = 0; p < 2; ++p) {
                    float s = acc[mi][2 * p][r] + bv[2 * p];
                    float t = acc[mi][2 * p + 1][r] + bv[2 * p + 1];
                    const size_t j = (col0 >> 1) + wc * 32 + p * 16 + ln15;
                    float2 zv = zin2[row * 512 + j];
                    float2 o; o.x = zv.x; o.y = zv.y * __expf(s) + t;
                    out2[row * 512 + j] = o;
                    sv += s;
                }
                sv += __shfl_xor(sv, 1, 64);
                sv += __shfl_xor(sv, 2, 64);
                sv += __shfl_xor(sv, 4, 64);
                sv += __shfl_xor(sv, 8, 64);
                if (ln15 == 0) atomicAdd(&ldout[row], sv);
            }
        }
    } else {
#pragma unroll
        for (int mi = 0; mi < 8; ++mi) {
#pragma unroll
            for (int r = 0; r < 4; ++r) {
                const size_t row = row0 + wr * 128 + mi * 16 + lq * 4 + r;
#pragma unroll
                for (int nf = 0; nf < 4; ++nf) {
                    const size_t col = col0 + wc * 64 + nf * 16 + ln15;
                    float v = acc[mi][nf][r] + bv[nf];
                    if (EPI == 0) {
                        float g = 0.5f * v * (1.0f + erff(v * 0.70710678118654752f));
                        outb[row * N + col] = f2bf(g);
                    } else {
                        outf[row * N + col] = v;
                    }
                }
            }
        }
    }
}

__global__ void cvt_bf16(const float* __restrict__ in, unsigned short* __restrict__ out, int n4) {
    const int stride = gridDim.x * blockDim.x;
    for (int i = blockIdx.x * blockDim.x + threadIdx.x; i < n4; i += stride) {
        float4 v = ((const float4*)in)[i];
        us4 o{ f2bf(v.x), f2bf(v.y), f2bf(v.z), f2bf(v.w) };
        ((us4*)out)[i] = o;
    }
}

// W3 interleave-by-16: out row c: q=c>>5,u=c&31; src = u<16 ? 16q+u : 512+16q+u-16
__global__ void cvt_w3i(const float* __restrict__ in, unsigned short* __restrict__ out, int n4) {
    const int stride = gridDim.x * blockDim.x;
    for (int i = blockIdx.x * blockDim.x + threadIdx.x; i < n4; i += stride) {
        int row = i >> 9;           // 512 float4 per 2048-col row
        int c4  = i & 511;
        int q = row >> 5, u = row & 31;
        int srcrow = (u < 16) ? (q * 16 + u) : (512 + q * 16 + u - 16);
        float4 v = ((const float4*)in)[(size_t)srcrow * 512 + c4];
        us4 o{ f2bf(v.x), f2bf(v.y), f2bf(v.z), f2bf(v.w) };
        ((us4*)out)[i] = o;
    }
}

// zm[row][i] = bf16(z[row][2i])
__global__ void pack_even(const float* __restrict__ z, unsigned short* __restrict__ zm, int n4) {
    const int stride = gridDim.x * blockDim.x;
    for (int i = blockIdx.x * blockDim.x + threadIdx.x; i < n4; i += stride) {
        float4 v = ((const float4*)z)[i];
        us2 o{ f2bf(v.x), f2bf(v.z) };
        ((us2*)zm)[i] = o;
    }
}

// b3 interleave-by-16 + ldout init
__global__ void prep3(const float* __restrict__ b3, float* __restrict__ b3i,
                      const float* __restrict__ ld, float* __restrict__ ldout, int nrow) {
    const int stride = gridDim.x * blockDim.x;
    int i = blockIdx.x * blockDim.x + threadIdx.x;
    if (i < 1024) {
        int q = i >> 5, u = i & 31;
        b3i[i] = b3[(u < 16) ? (q * 16 + u) : (512 + q * 16 + u - 16)];
    }
    for (int r = i; r < nrow; r += stride) ldout[r] = ld[r];
}

extern "C" void kernel_launch(void* const* d_in, const int* in_sizes, int n_in,
                              void* d_out, int out_size, void* d_ws, size_t ws_size,
                              hipStream_t stream)
{
    const float* z  = (const float*)d_in[0];
    const float* ld = (const float*)d_in[1];
    const float* W1 = (const float*)d_in[2];
    const float* b1 = (const float*)d_in[3];
    const float* W2 = (const float*)d_in[4];
    const float* b2 = (const float*)d_in[5];
    const float* W3 = (const float*)d_in[6];
    const float* b3 = (const float*)d_in[7];

    float* out   = (float*)d_out;
    float* zout  = out;
    float* ldout = out + (size_t)16384 * 1024;

    char* w = (char*)d_ws;
    unsigned short* zm  = (unsigned short*)w; w += (size_t)16384 * 512 * 2;
    unsigned short* w1b = (unsigned short*)w; w += (size_t)2048 * 512 * 2;
    unsigned short* w2b = (unsigned short*)w; w += (size_t)2048 * 2048 * 2;
    unsigned short* w3i = (unsigned short*)w; w += (size_t)1024 * 2048 * 2;
    unsigned short* h1  = (unsigned short*)w; w += (size_t)16384 * 2048 * 2;
    unsigned short* h2  = (unsigned short*)w; w += (size_t)16384 * 2048 * 2;
    float*          b3i = (float*)w;          w += 1024 * 4;

    (void)hipFuncSetAttribute((const void*)&gemm256<0, 512,  2048>,
                              hipFuncAttributeMaxDynamicSharedMemorySize, 131072);
    (void)hipFuncSetAttribute((const void*)&gemm256<0, 2048, 2048>,
                              hipFuncAttributeMaxDynamicSharedMemorySize, 131072);
    (void)hipFuncSetAttribute((const void*)&gemm256<2, 2048, 1024>,
                              hipFuncAttributeMaxDynamicSharedMemorySize, 131072);

    cvt_bf16 <<<512,  256, 0, stream>>>(W1, w1b, 2048 * 512 / 4);
    cvt_bf16 <<<2048, 256, 0, stream>>>(W2, w2b, 2048 * 2048 / 4);
    cvt_w3i  <<<1024, 256, 0, stream>>>(W3, w3i, 1024 * 2048 / 4);
    pack_even<<<2048, 256, 0, stream>>>(z, zm, 16384 * 1024 / 4);
    prep3    <<<64,   256, 0, stream>>>(b3, b3i, ld, ldout, 16384);

    gemm256<0, 512,  2048><<<dim3(8, 64), 512, 131072, stream>>>(zm, w1b, b1, h1, nullptr, nullptr, nullptr);
    gemm256<0, 2048, 2048><<<dim3(8, 64), 512, 131072, stream>>>(h1, w2b, b2, h2, nullptr, nullptr, nullptr);
    gemm256<2, 2048, 1024><<<dim3(4, 64), 512, 131072, stream>>>(h2, w3i, b3i, nullptr, zout, z, ldout);
}